// Round 6
// baseline (121.604 us; speedup 1.0000x reference)
//
#include <hip/hip_runtime.h>

typedef _Float16 half_t;
typedef _Float16 halfv8 __attribute__((ext_vector_type(8)));
typedef _Float16 halfv4 __attribute__((ext_vector_type(4)));
typedef float    floatv4 __attribute__((ext_vector_type(4)));
typedef unsigned int uint;
typedef uint uintv4 __attribute__((ext_vector_type(4)));

#define NODES 32
#define FIN   128
#define EPG   512
#define NBS   4096
#define ETOT  (NBS*EPG)
#define NTOT  (NBS*NODES)   // 131072 nodes
#define HID   1024
#define KDIM  4096          // FIN*NODES
#define NCLS  10

// lin1 GEMM geometry (m201-style 8-phase)
#define BM 256
#define BN 256
#define BK 64
#define KS 4
#define KSLEN (KDIM/KS)  // 1024
#define NT (KSLEN/BK)    // 16 K-tiles

#define GLDS16(g, l)                                                        \
  __builtin_amdgcn_global_load_lds(                                         \
      (const __attribute__((address_space(1))) unsigned int*)(g),           \
      (__attribute__((address_space(3))) unsigned int*)(l), 16, 0, 0)

// ---------------------------------------------------------------------------
// prep: lin1_w fp32 [o][f*32+n] -> fp16 permuted [o][n*128+f]; also gconv fp16
__global__ __launch_bounds__(256) void prep_w1(const float* __restrict__ w1,
                                               half_t* __restrict__ w1p,
                                               const float* __restrict__ gw,
                                               half_t* __restrict__ gw16) {
  __shared__ float tmp[FIN * 33];
  const int o = blockIdx.x, t = threadIdx.x;
  if (t < 16) {
    const int i = o * 16 + t;
    gw16[i] = (half_t)gw[i];
  }
  const floatv4* src = (const floatv4*)(w1 + (size_t)o * KDIM);
  for (int i = t; i < KDIM / 4; i += 256) {
    floatv4 v = src[i];
    const int f = i >> 3;
    const int n = (i & 7) * 4;
#pragma unroll
    for (int q = 0; q < 4; ++q) tmp[f * 33 + n + q] = v[q];
  }
  __syncthreads();
  half_t* dst = w1p + (size_t)o * KDIM;
  for (int i = t; i < KDIM; i += 256) {
    const int n = i >> 7, f = i & 127;
    dst[i] = (half_t)tmp[f * 33 + n];
  }
}

// ---------------------------------------------------------------------------
// zw_gemm: Zt[o][node] = (X @ W^T)^T, fp16. No LDS, no barriers.
// Wave = 16 node-rows; all x loads batch-issued (one latency exposure).
__global__ __launch_bounds__(256, 3) void zw_gemm(
    const float* __restrict__ x, const half_t* __restrict__ gw16,
    half_t* __restrict__ Zt) {
  const int t = threadIdx.x, w = t >> 6, l = t & 63;
  const int lr = l & 15, lk = l >> 4;
  const size_t base = (size_t)blockIdx.x * 64 + w * 16;

  const float* xp = x + (base + lr) * FIN;
  floatv4 xq[8];
#pragma unroll
  for (int kk = 0; kk < 4; ++kk) {
    xq[kk * 2]     = *(const floatv4*)(xp + kk * 32 + lk * 8);
    xq[kk * 2 + 1] = *(const floatv4*)(xp + kk * 32 + lk * 8 + 4);
  }
  floatv4 acc[8] = {};
#pragma unroll
  for (int kk = 0; kk < 4; ++kk) {
    halfv8 af;
#pragma unroll
    for (int q = 0; q < 4; ++q) {
      af[q]     = (half_t)xq[kk * 2][q];
      af[q + 4] = (half_t)xq[kk * 2 + 1][q];
    }
    halfv8 bf[8];
#pragma unroll
    for (int nt = 0; nt < 8; ++nt)
      bf[nt] = *(const halfv8*)(gw16 + (nt * 16 + lr) * FIN + kk * 32 + lk * 8);
#pragma unroll
    for (int nt = 0; nt < 8; ++nt)
      acc[nt] = __builtin_amdgcn_mfma_f32_16x16x32_f16(af, bf[nt], acc[nt], 0, 0, 0);
  }
#pragma unroll
  for (int nt = 0; nt < 8; ++nt) {
    halfv4 h = {(half_t)acc[nt][0], (half_t)acc[nt][1],
                (half_t)acc[nt][2], (half_t)acc[nt][3]};
    *(halfv4*)(Zt + (size_t)(nt * 16 + lr) * NTOT + base + lk * 4) = h;
  }
}

// ---------------------------------------------------------------------------
// gin_mix: H_g = relu((I + C_g) @ Z_g + b). Wave per graph; Zt B-frags
// batch-issued; histogram in wave-private LDS; single K=32 MFMA pass.
__global__ __launch_bounds__(256, 3) void gin_mix(
    const half_t* __restrict__ Zt, const int* __restrict__ ei,
    const float* __restrict__ gb, half_t* __restrict__ H) {
  __shared__ uint cnt[4][512];
  const int t = threadIdx.x, w = t >> 6, l = t & 63;
  const int lr = l & 15, lk = l >> 4;
  const int g = blockIdx.x * 4 + w;

  // Zt fragments first (longest-latency loads, issue early)
  halfv8 bf[8];
#pragma unroll
  for (int nt = 0; nt < 8; ++nt)
    bf[nt] = *(const halfv8*)(Zt + (size_t)(nt * 16 + lr) * NTOT +
                              (size_t)g * 32 + lk * 8);
  // edges
  const int* sp = ei + (size_t)g * EPG;
  const int* dp = ei + (size_t)ETOT + (size_t)g * EPG;
  uintv4 s0 = *(const uintv4*)(sp + l * 8);
  uintv4 s1 = *(const uintv4*)(sp + l * 8 + 4);
  uintv4 d0 = *(const uintv4*)(dp + l * 8);
  uintv4 d1 = *(const uintv4*)(dp + l * 8 + 4);
  {
    uintv4* c4 = (uintv4*)cnt[w];
    uintv4 z = {0, 0, 0, 0};
    c4[l] = z;
    c4[l + 64] = z;
  }
#pragma unroll
  for (int q = 0; q < 4; ++q) {
    uint p0 = (d0[q] & 31) * 32 + (s0[q] & 31);
    atomicAdd(&cnt[w][p0 >> 1], 1u << ((p0 & 1) * 16));
    uint p1 = (d1[q] & 31) * 32 + (s1[q] & 31);
    atomicAdd(&cnt[w][p1 >> 1], 1u << ((p1 & 1) * 16));
  }
  const unsigned short* c16 = (const unsigned short*)cnt[w];
  halfv8 am[2];
#pragma unroll
  for (int mt = 0; mt < 2; ++mt) {
    const int i = mt * 16 + lr;
#pragma unroll
    for (int q = 0; q < 8; ++q) {
      const int j = lk * 8 + q;
      float c = (float)c16[i * 32 + j] + ((j == i) ? 1.f : 0.f);
      am[mt][q] = (half_t)c;
    }
  }
  floatv4 acc2[2][8] = {};
#pragma unroll
  for (int nt = 0; nt < 8; ++nt)
#pragma unroll
    for (int mt = 0; mt < 2; ++mt)
      acc2[mt][nt] = __builtin_amdgcn_mfma_f32_16x16x32_f16(am[mt], bf[nt],
                                                            acc2[mt][nt], 0, 0, 0);
  half_t* Hg = H + (size_t)g * KDIM;
#pragma unroll
  for (int nt = 0; nt < 8; ++nt) {
    const float bias = gb[nt * 16 + lr];
#pragma unroll
    for (int mt = 0; mt < 2; ++mt)
#pragma unroll
      for (int q = 0; q < 4; ++q) {
        const int m = mt * 16 + lk * 4 + q;
        const float v = acc2[mt][nt][q] + bias;
        Hg[m * FIN + nt * 16 + lr] = (half_t)(v > 0.f ? v : 0.f);
      }
  }
}

// ---------------------------------------------------------------------------
// lin1 GEMM: m201-style 8-phase. LDS = [2 buf][2 khalf][256 rows][32 cols]
// per operand (128 KB). 4 phases per K-tile: (m0,k0)(m1,k0)(m0,k1)(m1,k1);
// each phase stages one K-half of tile t+1; vmcnt(4) at phases 0 and 2.
__global__ __launch_bounds__(512, 2) void lin1_gemm(
    const half_t* __restrict__ A, const half_t* __restrict__ B,
    half_t* __restrict__ Cbase) {
  __shared__ __attribute__((aligned(16))) half_t As[2 * 2 * 256 * 32];  // 64 KB
  __shared__ __attribute__((aligned(16))) half_t Bs[2 * 2 * 256 * 32];  // 64 KB

  const int t = threadIdx.x;
  const int orig = blockIdx.x;                       // 256 blocks, 1/CU
  const int wg = (orig & 7) * 32 + (orig >> 3);      // bijective XCD swizzle
  const int mt = wg & 15, rest = wg >> 4;
  const int nt_ = rest & 3, ks = rest >> 2;
  const int m0 = mt * BM, n0 = nt_ * BN, k0 = ks * KSLEN;

  // staging map: chunk L in [0,1024): row=L>>2, 16B chunk c=(L&3)^(row&3)
  const int L0 = t, L1 = t + 512;
  const int r0 = L0 >> 2, c0 = (L0 & 3) ^ (r0 & 3);
  const int r1 = L1 >> 2, c1 = (L1 & 3) ^ (r1 & 3);
  const half_t* srcA0 = A + (size_t)(m0 + r0) * KDIM + k0 + c0 * 8;
  const half_t* srcA1 = A + (size_t)(m0 + r1) * KDIM + k0 + c1 * 8;
  const half_t* srcB0 = B + (size_t)(n0 + r0) * KDIM + k0 + c0 * 8;
  const half_t* srcB1 = B + (size_t)(n0 + r1) * KDIM + k0 + c1 * 8;

#define STAGE_A(buf, kh, tt)                                                  \
  { GLDS16(srcA0 + (tt) * BK + (kh) * 32, &As[(buf) * 16384 + (kh) * 8192 + L0 * 8]); \
    GLDS16(srcA1 + (tt) * BK + (kh) * 32, &As[(buf) * 16384 + (kh) * 8192 + L1 * 8]); }
#define STAGE_B(buf, kh, tt)                                                  \
  { GLDS16(srcB0 + (tt) * BK + (kh) * 32, &Bs[(buf) * 16384 + (kh) * 8192 + L0 * 8]); \
    GLDS16(srcB1 + (tt) * BK + (kh) * 32, &Bs[(buf) * 16384 + (kh) * 8192 + L1 * 8]); }

  const int w = t >> 6, l = t & 63, lr = l & 15, lk = l >> 4;
  const int wm = (w >> 2) * 128, wn = (w & 3) * 64;

  floatv4 acc[8][4] = {};

  // prologue: all 4 halves of tile 0
  STAGE_A(0, 0, 0) STAGE_B(0, 0, 0) STAGE_A(0, 1, 0) STAGE_B(0, 1, 0)

#define PHASE(cur, mh, kh, DO_WAIT, STAGE_STMT)                               \
  {                                                                           \
    if (DO_WAIT) asm volatile("s_waitcnt vmcnt(4)" ::: "memory");             \
    __builtin_amdgcn_s_barrier();                                             \
    __builtin_amdgcn_sched_barrier(0);                                        \
    halfv8 af[4], bf[4];                                                      \
    _Pragma("unroll")                                                         \
    for (int nf = 0; nf < 4; ++nf) {                                          \
      const int row = wn + nf * 16 + lr;                                      \
      bf[nf] = *(const halfv8*)&Bs[(cur) * 16384 + (kh) * 8192 + row * 32 +   \
                                   ((lk ^ (row & 3)) * 8)];                   \
    }                                                                         \
    _Pragma("unroll")                                                         \
    for (int mf = 0; mf < 4; ++mf) {                                          \
      const int row = wm + (mh) * 64 + mf * 16 + lr;                          \
      af[mf] = *(const halfv8*)&As[(cur) * 16384 + (kh) * 8192 + (row & 127) * 32 + \
                                   ((lk ^ (row & 3)) * 8)];                   \
    }                                                                         \
    STAGE_STMT;                                                               \
    __builtin_amdgcn_s_setprio(1);                                            \
    _Pragma("unroll")                                                         \
    for (int mf = 0; mf < 4; ++mf)                                            \
      _Pragma("unroll")                                                       \
      for (int nf = 0; nf < 4; ++nf)                                          \
        acc[(mh) * 4 + mf][nf] = __builtin_amdgcn_mfma_f32_16x16x32_f16(      \
            af[mf], bf[nf], acc[(mh) * 4 + mf][nf], 0, 0, 0);                 \
    __builtin_amdgcn_s_setprio(0);                                            \
  }

  // NOTE: A LDS rows are 0..255 (both wave M-halves); (row & 127) is wrong for
  // waves 4-7 -- A rows wm+mh*64+... span 0..255 and As holds 256 rows, so use
  // the full row index. (row & 127) would alias; use row directly:
#undef PHASE
#define PHASE(cur, mh, kh, DO_WAIT, STAGE_STMT)                               \
  {                                                                           \
    if (DO_WAIT) asm volatile("s_waitcnt vmcnt(4)" ::: "memory");             \
    __builtin_amdgcn_s_barrier();                                             \
    __builtin_amdgcn_sched_barrier(0);                                        \
    halfv8 af[4], bf[4];                                                      \
    _Pragma("unroll")                                                         \
    for (int nf = 0; nf < 4; ++nf) {                                          \
      const int row = wn + nf * 16 + lr;                                      \
      bf[nf] = *(const halfv8*)&Bs[(cur) * 16384 + (kh) * 8192 + row * 32 +   \
                                   ((lk ^ (row & 3)) * 8)];                   \
    }                                                                         \
    _Pragma("unroll")                                                         \
    for (int mf = 0; mf < 4; ++mf) {                                          \
      const int row = wm + (mh) * 64 + mf * 16 + lr;                          \
      af[mf] = *(const halfv8*)&As[(cur) * 16384 + (kh) * 8192 + row * 32 +   \
                                   ((lk ^ (row & 3)) * 8)];                   \
    }                                                                         \
    STAGE_STMT;                                                               \
    __builtin_amdgcn_s_setprio(1);                                            \
    _Pragma("unroll")                                                         \
    for (int mf = 0; mf < 4; ++mf)                                            \
      _Pragma("unroll")                                                       \
      for (int nf = 0; nf < 4; ++nf)                                          \
        acc[(mh) * 4 + mf][nf] = __builtin_amdgcn_mfma_f32_16x16x32_f16(      \
            af[mf], bf[nf], acc[(mh) * 4 + mf][nf], 0, 0, 0);                 \
    __builtin_amdgcn_s_setprio(0);                                            \
  }

  for (int kt = 0; kt < NT; ++kt) {
    const int cur = kt & 1, nxt = cur ^ 1;
    const int ttn = (kt + 1 < NT) ? (kt + 1) : 0;  // dummy tail keeps counts uniform
    PHASE(cur, 0, 0, 1, STAGE_A(nxt, 0, ttn))
    PHASE(cur, 1, 0, 0, STAGE_B(nxt, 0, ttn))
    PHASE(cur, 0, 1, 1, STAGE_A(nxt, 1, ttn))
    PHASE(cur, 1, 1, 0, STAGE_B(nxt, 1, ttn))
  }

  half_t* C = Cbase + (size_t)ks * ((size_t)NBS * HID);
#pragma unroll
  for (int mf = 0; mf < 8; ++mf)
#pragma unroll
    for (int nf = 0; nf < 4; ++nf) {
      const int n = n0 + wn + nf * 16 + lr;
#pragma unroll
      for (int q = 0; q < 4; ++q) {
        const int m = m0 + wm + mf * 16 + lk * 4 + q;
        C[(size_t)m * HID + n] = (half_t)acc[mf][nf][q];
      }
    }
#undef PHASE
#undef STAGE_A
#undef STAGE_B
}

// ---------------------------------------------------------------------------
// head: hidden = relu(sum_ks C[ks] + b1); logits = hidden @ w2^T + b2; softmax
__global__ __launch_bounds__(256) void head(
    const half_t* __restrict__ Cb, const float* __restrict__ b1,
    const float* __restrict__ w2, const float* __restrict__ b2,
    float* __restrict__ out) {
  __shared__ __attribute__((aligned(16))) float w2s[NCLS * HID];
  const int t = threadIdx.x;
  {
    const floatv4* s4 = (const floatv4*)w2;
    floatv4* d4 = (floatv4*)w2s;
    for (int i = t; i < (NCLS * HID) / 4; i += 256) d4[i] = s4[i];
  }
  __syncthreads();
  const int w = t >> 6, l = t & 63;
  const int row = blockIdx.x * 4 + w;

  float r[16];
#pragma unroll
  for (int jj = 0; jj < 4; ++jj) {
    floatv4 bb = *(const floatv4*)&b1[jj * 256 + l * 4];
    float s[4] = {bb[0], bb[1], bb[2], bb[3]};
#pragma unroll
    for (int p = 0; p < KS; ++p) {
      const half_t* cp = Cb + (size_t)p * ((size_t)NBS * HID) + (size_t)row * HID;
      halfv4 u = *(const halfv4*)&cp[jj * 256 + l * 4];
#pragma unroll
      for (int q = 0; q < 4; ++q) s[q] += (float)u[q];
    }
#pragma unroll
    for (int q = 0; q < 4; ++q) r[jj * 4 + q] = s[q] > 0.f ? s[q] : 0.f;
  }
  float lg[10];
#pragma unroll
  for (int c = 0; c < NCLS; ++c) {
    float p = 0.f;
#pragma unroll
    for (int jj = 0; jj < 4; ++jj) {
      floatv4 wv = *(const floatv4*)&w2s[c * HID + jj * 256 + l * 4];
      p += r[jj * 4 + 0] * wv[0] + r[jj * 4 + 1] * wv[1] +
           r[jj * 4 + 2] * wv[2] + r[jj * 4 + 3] * wv[3];
    }
#pragma unroll
    for (int off = 32; off >= 1; off >>= 1) p += __shfl_xor(p, off);
    lg[c] = p + b2[c];
  }
  float mx = lg[0];
#pragma unroll
  for (int c = 1; c < NCLS; ++c) mx = fmaxf(mx, lg[c]);
  float sum = 0.f;
#pragma unroll
  for (int c = 0; c < NCLS; ++c) { lg[c] = __expf(lg[c] - mx); sum += lg[c]; }
  const float inv = 1.f / sum;
  float myv = 0.f;
#pragma unroll
  for (int c = 0; c < NCLS; ++c) myv = (l == c) ? lg[c] * inv : myv;
  if (l < NCLS) out[(size_t)row * NCLS + l] = myv;
}

// ---------------------------------------------------------------------------
extern "C" void kernel_launch(void* const* d_in, const int* in_sizes, int n_in,
                              void* d_out, int out_size, void* d_ws, size_t ws_size,
                              hipStream_t stream) {
  (void)in_sizes; (void)n_in; (void)out_size; (void)ws_size;
  const float* x  = (const float*)d_in[0];
  const int*   ei = (const int*)d_in[1];
  const float* gw = (const float*)d_in[2];
  const float* gb = (const float*)d_in[3];
  const float* w1 = (const float*)d_in[4];
  const float* b1 = (const float*)d_in[5];
  const float* w2 = (const float*)d_in[6];
  const float* b2 = (const float*)d_in[7];
  float* out = (float*)d_out;

  char* ws = (char*)d_ws;
  // Zt (32 MB) aliases C (KS x 8 MB): Zt is dead before lin1_gemm writes C.
  half_t* Zt   = (half_t*)(ws);
  half_t* C    = (half_t*)(ws);
  half_t* H    = (half_t*)(ws + 33554432);             // 32 MB
  half_t* w1p  = (half_t*)(ws + 67108864);             //  8 MB
  half_t* gw16 = (half_t*)(ws + 75497472);             // 32 KB

  prep_w1  <<<dim3(HID),      dim3(256), 0, stream>>>(w1, w1p, gw, gw16);
  zw_gemm  <<<dim3(NTOT/64),  dim3(256), 0, stream>>>(x, gw16, Zt);
  gin_mix  <<<dim3(NBS/4),    dim3(256), 0, stream>>>(Zt, ei, gb, H);
  lin1_gemm<<<dim3(16*4*KS),  dim3(512), 0, stream>>>(H, w1p, C);
  head     <<<dim3(NBS/4),    dim3(256), 0, stream>>>(C, b1, w2, b2, out);
}

// Round 7
// 98.960 us; speedup vs baseline: 1.2288x; 1.2288x over previous
//
#include <hip/hip_runtime.h>

typedef _Float16 half_t;
typedef _Float16 halfv8 __attribute__((ext_vector_type(8)));
typedef _Float16 halfv4 __attribute__((ext_vector_type(4)));
typedef float    floatv4 __attribute__((ext_vector_type(4)));
typedef unsigned int uint;
typedef uint uintv4 __attribute__((ext_vector_type(4)));

#define NODES 32
#define FIN   128
#define EPG   512
#define NBS   4096
#define ETOT  (NBS*EPG)
#define HID   1024
#define KDIM  4096          // FIN*NODES
#define NCLS  10
#define YP    36            // LDS pitch (halves) for the Z^T / H^T bounce

// lin1 GEMM geometry (8-phase)
#define BM 256
#define BN 256
#define BK 64
#define KS 4
#define KSLEN (KDIM/KS)  // 1024
#define NT (KSLEN/BK)    // 16 K-tiles

#define GLDS16(g, l)                                                        \
  __builtin_amdgcn_global_load_lds(                                         \
      (const __attribute__((address_space(1))) unsigned int*)(g),           \
      (__attribute__((address_space(3))) unsigned int*)(l), 16, 0, 0)

// ---------------------------------------------------------------------------
// prep: pure fp32->fp16 casts. H layout [g][o*32+node] makes lin1's B matrix
// the ORIGINAL lin1_w layout -> no transpose needed anywhere.
__global__ __launch_bounds__(256) void prep_cvt(const float* __restrict__ w1,
                                                half_t* __restrict__ w1p,
                                                const float* __restrict__ gw,
                                                half_t* __restrict__ gw16) {
  const size_t q = (size_t)blockIdx.x * 256 + threadIdx.x;  // 1052672 quads
  const float* s;
  half_t* d;
  size_t off;
  if (q < 1048576) { s = w1; d = w1p; off = q; }
  else             { s = gw; d = gw16; off = q - 1048576; }
  floatv4 v = *(const floatv4*)(s + off * 4);
  halfv4 h = {(half_t)v[0], (half_t)v[1], (half_t)v[2], (half_t)v[3]};
  *(halfv4*)(d + off * 4) = h;
}

// ---------------------------------------------------------------------------
// gin_fused v3: H_g = relu((I + C_g) @ (x_g @ W^T) + b), stored [g][o*32+m].
// Wave per graph. Epilogue repacks H^T through the same LDS buffer used for
// the Z^T bounce -> global stores are 16B/lane, 1KB/instr contiguous.
__global__ __launch_bounds__(256, 3) void gin_fused(
    const float* __restrict__ x, const int* __restrict__ ei,
    const half_t* __restrict__ gw16, const float* __restrict__ gb,
    half_t* __restrict__ H) {
  __shared__ __attribute__((aligned(16))) half_t Yt[4][FIN * YP];  // 36864 B
  __shared__ __attribute__((aligned(16))) uint  cnt[4][512];       //  8192 B

  const int t = threadIdx.x, w = t >> 6, l = t & 63;
  const int lr = l & 15, lk = l >> 4;
  const int g = blockIdx.x * 4 + w;

  // (a) x tile (32x128 fp32) -> registers, batch-issued
  const float* xg = x + (size_t)g * (NODES * FIN);
  floatv4 xr[2][4][2];
#pragma unroll
  for (int mt = 0; mt < 2; ++mt)
#pragma unroll
    for (int kk = 0; kk < 4; ++kk) {
      const float* p = xg + (mt * 16 + lr) * FIN + kk * 32 + lk * 8;
      xr[mt][kk][0] = *(const floatv4*)p;
      xr[mt][kk][1] = *(const floatv4*)(p + 4);
    }
  // (b) edges (contiguous per graph; local id = idx & 31)
  const int* sp = ei + (size_t)g * EPG;
  const int* dp = ei + (size_t)ETOT + (size_t)g * EPG;
  uintv4 s0 = *(const uintv4*)(sp + l * 8);
  uintv4 s1 = *(const uintv4*)(sp + l * 8 + 4);
  uintv4 d0 = *(const uintv4*)(dp + l * 8);
  uintv4 d1 = *(const uintv4*)(dp + l * 8 + 4);

  // (c) zero wave-private histogram; accumulate packed-u16 counts
  {
    uintv4* c4 = (uintv4*)cnt[w];
    uintv4 z = {0, 0, 0, 0};
    c4[l] = z;
    c4[l + 64] = z;
  }
#pragma unroll
  for (int q = 0; q < 4; ++q) {
    uint p0 = (d0[q] & 31) * 32 + (s0[q] & 31);
    atomicAdd(&cnt[w][p0 >> 1], 1u << ((p0 & 1) * 16));
    uint p1 = (d1[q] & 31) * 32 + (s1[q] & 31);
    atomicAdd(&cnt[w][p1 >> 1], 1u << ((p1 & 1) * 16));
  }

  // (d) x -> fp16 A-fragments
  halfv8 af[2][4];
#pragma unroll
  for (int mt = 0; mt < 2; ++mt)
#pragma unroll
    for (int kk = 0; kk < 4; ++kk) {
      halfv8 h;
#pragma unroll
      for (int q = 0; q < 4; ++q) {
        h[q]     = (half_t)xr[mt][kk][0][q];
        h[q + 4] = (half_t)xr[mt][kk][1][q];
      }
      af[mt][kk] = h;
    }

  // (e) MFMA1: Z[j][o] = sum_f x[j][f] W[o][f]; W frags from global (L1-hot)
  floatv4 acc[2][8] = {};
#pragma unroll
  for (int kk = 0; kk < 4; ++kk) {
    halfv8 bfk[8];
#pragma unroll
    for (int nt = 0; nt < 8; ++nt)
      bfk[nt] = *(const halfv8*)(gw16 + (nt * 16 + lr) * FIN + kk * 32 + lk * 8);
#pragma unroll
    for (int nt = 0; nt < 8; ++nt)
#pragma unroll
      for (int mt = 0; mt < 2; ++mt)
        acc[mt][nt] = __builtin_amdgcn_mfma_f32_16x16x32_f16(af[mt][kk], bfk[nt],
                                                             acc[mt][nt], 0, 0, 0);
  }

  // (f) bounce Z^T into this wave's LDS: Yt[o][j]
  half_t* yw = Yt[w];
#pragma unroll
  for (int mt = 0; mt < 2; ++mt)
#pragma unroll
    for (int nt = 0; nt < 8; ++nt) {
      halfv4 h = {(half_t)acc[mt][nt][0], (half_t)acc[mt][nt][1],
                  (half_t)acc[mt][nt][2], (half_t)acc[mt][nt][3]};
      *(halfv4*)&yw[(nt * 16 + lr) * YP + mt * 16 + lk * 4] = h;
    }

  // (g) M' = I + C fragments from histogram
  const unsigned short* c16 = (const unsigned short*)cnt[w];
  halfv8 am[2];
#pragma unroll
  for (int mt = 0; mt < 2; ++mt) {
    const int i = mt * 16 + lr;
#pragma unroll
    for (int q = 0; q < 8; ++q) {
      const int j = lk * 8 + q;
      float c = (float)c16[i * 32 + j] + ((j == i) ? 1.f : 0.f);
      am[mt][q] = (half_t)c;
    }
  }

  // (h) MFMA2: H[i][o] = sum_j M'[i][j] Z[j][o]
  floatv4 acc2[2][8] = {};
#pragma unroll
  for (int nt = 0; nt < 8; ++nt) {
    halfv8 bf = *(const halfv8*)&yw[(nt * 16 + lr) * YP + lk * 8];
#pragma unroll
    for (int mt = 0; mt < 2; ++mt)
      acc2[mt][nt] = __builtin_amdgcn_mfma_f32_16x16x32_f16(am[mt], bf,
                                                            acc2[mt][nt], 0, 0, 0);
  }
  __builtin_amdgcn_sched_barrier(0);  // keep H^T writes below all Yt reads

  // (i) bias + relu; overwrite same buffer with H^T[o][m] (same index expr)
#pragma unroll
  for (int nt = 0; nt < 8; ++nt) {
    const float bias = gb[nt * 16 + lr];
#pragma unroll
    for (int mt = 0; mt < 2; ++mt) {
      halfv4 h;
#pragma unroll
      for (int q = 0; q < 4; ++q) {
        const float v = acc2[mt][nt][q] + bias;
        h[q] = (half_t)(v > 0.f ? v : 0.f);
      }
      *(halfv4*)&yw[(nt * 16 + lr) * YP + mt * 16 + lk * 4] = h;
    }
  }
  __builtin_amdgcn_sched_barrier(0);

  // (j) linear readback -> fat coalesced stores: H[g][o*32+m], 1KB/instr
  half_t* Hg = H + (size_t)g * KDIM;
#pragma unroll
  for (int c = 0; c < 8; ++c) {
    const int ch = c * 64 + l;          // 512 chunks of 8 halves
    const int o = ch >> 2, m0 = (ch & 3) * 8;
    halfv8 v = *(const halfv8*)&yw[o * YP + m0];
    *(halfv8*)(Hg + ch * 8) = v;
  }
}

// ---------------------------------------------------------------------------
// lin1 GEMM: 8-phase, 256x256 tile, BK=64 (2 K-halves), split-K=4,
// double-buffered 128 KB LDS, chunk-XOR swizzle, counted vmcnt(4).
__global__ __launch_bounds__(512, 2) void lin1_gemm(
    const half_t* __restrict__ A, const half_t* __restrict__ B,
    half_t* __restrict__ Cbase) {
  __shared__ __attribute__((aligned(16))) half_t As[2 * 2 * 256 * 32];  // 64 KB
  __shared__ __attribute__((aligned(16))) half_t Bs[2 * 2 * 256 * 32];  // 64 KB

  const int t = threadIdx.x;
  const int orig = blockIdx.x;                       // 256 blocks, 1/CU
  const int wg = (orig & 7) * 32 + (orig >> 3);      // bijective XCD swizzle
  const int mt = wg & 15, rest = wg >> 4;
  const int nt_ = rest & 3, ks = rest >> 2;
  const int m0 = mt * BM, n0 = nt_ * BN, k0 = ks * KSLEN;

  // staging map: chunk L in [0,1024): row=L>>2, 16B chunk c=(L&3)^(row&3)
  const int L0 = t, L1 = t + 512;
  const int r0 = L0 >> 2, c0 = (L0 & 3) ^ (r0 & 3);
  const int r1 = L1 >> 2, c1 = (L1 & 3) ^ (r1 & 3);
  const half_t* srcA0 = A + (size_t)(m0 + r0) * KDIM + k0 + c0 * 8;
  const half_t* srcA1 = A + (size_t)(m0 + r1) * KDIM + k0 + c1 * 8;
  const half_t* srcB0 = B + (size_t)(n0 + r0) * KDIM + k0 + c0 * 8;
  const half_t* srcB1 = B + (size_t)(n0 + r1) * KDIM + k0 + c1 * 8;

#define STAGE_A(buf, kh, tt)                                                  \
  { GLDS16(srcA0 + (tt) * BK + (kh) * 32, &As[(buf) * 16384 + (kh) * 8192 + L0 * 8]); \
    GLDS16(srcA1 + (tt) * BK + (kh) * 32, &As[(buf) * 16384 + (kh) * 8192 + L1 * 8]); }
#define STAGE_B(buf, kh, tt)                                                  \
  { GLDS16(srcB0 + (tt) * BK + (kh) * 32, &Bs[(buf) * 16384 + (kh) * 8192 + L0 * 8]); \
    GLDS16(srcB1 + (tt) * BK + (kh) * 32, &Bs[(buf) * 16384 + (kh) * 8192 + L1 * 8]); }

  const int w = t >> 6, l = t & 63, lr = l & 15, lk = l >> 4;
  const int wm = (w >> 2) * 128, wn = (w & 3) * 64;

  floatv4 acc[8][4] = {};

  STAGE_A(0, 0, 0) STAGE_B(0, 0, 0) STAGE_A(0, 1, 0) STAGE_B(0, 1, 0)

#define PHASE(cur, mh, kh, DO_WAIT, STAGE_STMT)                               \
  {                                                                           \
    if (DO_WAIT) asm volatile("s_waitcnt vmcnt(4)" ::: "memory");             \
    __builtin_amdgcn_s_barrier();                                             \
    __builtin_amdgcn_sched_barrier(0);                                        \
    halfv8 af[4], bf[4];                                                      \
    _Pragma("unroll")                                                         \
    for (int nf = 0; nf < 4; ++nf) {                                          \
      const int row = wn + nf * 16 + lr;                                      \
      bf[nf] = *(const halfv8*)&Bs[(cur) * 16384 + (kh) * 8192 + row * 32 +   \
                                   ((lk ^ (row & 3)) * 8)];                   \
    }                                                                         \
    _Pragma("unroll")                                                         \
    for (int mf = 0; mf < 4; ++mf) {                                          \
      const int row = wm + (mh) * 64 + mf * 16 + lr;                          \
      af[mf] = *(const halfv8*)&As[(cur) * 16384 + (kh) * 8192 + row * 32 +   \
                                   ((lk ^ (row & 3)) * 8)];                   \
    }                                                                         \
    STAGE_STMT;                                                               \
    __builtin_amdgcn_s_setprio(1);                                            \
    _Pragma("unroll")                                                         \
    for (int mf = 0; mf < 4; ++mf)                                            \
      _Pragma("unroll")                                                       \
      for (int nf = 0; nf < 4; ++nf)                                          \
        acc[(mh) * 4 + mf][nf] = __builtin_amdgcn_mfma_f32_16x16x32_f16(      \
            af[mf], bf[nf], acc[(mh) * 4 + mf][nf], 0, 0, 0);                 \
    __builtin_amdgcn_s_setprio(0);                                            \
  }

  for (int kt = 0; kt < NT; ++kt) {
    const int cur = kt & 1, nxt = cur ^ 1;
    const int ttn = (kt + 1 < NT) ? (kt + 1) : 0;  // dummy tail keeps counts uniform
    PHASE(cur, 0, 0, 1, STAGE_A(nxt, 0, ttn))
    PHASE(cur, 1, 0, 0, STAGE_B(nxt, 0, ttn))
    PHASE(cur, 0, 1, 1, STAGE_A(nxt, 1, ttn))
    PHASE(cur, 1, 1, 0, STAGE_B(nxt, 1, ttn))
  }

  half_t* C = Cbase + (size_t)ks * ((size_t)NBS * HID);
#pragma unroll
  for (int mf = 0; mf < 8; ++mf)
#pragma unroll
    for (int nf = 0; nf < 4; ++nf) {
      const int n = n0 + wn + nf * 16 + lr;
#pragma unroll
      for (int q = 0; q < 4; ++q) {
        const int m = m0 + wm + mf * 16 + lk * 4 + q;
        C[(size_t)m * HID + n] = (half_t)acc[mf][nf][q];
      }
    }
#undef PHASE
#undef STAGE_A
#undef STAGE_B
}

// ---------------------------------------------------------------------------
// head: hidden = relu(sum_ks C[ks] + b1); logits = hidden @ w2^T + b2; softmax
__global__ __launch_bounds__(256) void head(
    const half_t* __restrict__ Cb, const float* __restrict__ b1,
    const float* __restrict__ w2, const float* __restrict__ b2,
    float* __restrict__ out) {
  __shared__ __attribute__((aligned(16))) float w2s[NCLS * HID];
  const int t = threadIdx.x;
  {
    const floatv4* s4 = (const floatv4*)w2;
    floatv4* d4 = (floatv4*)w2s;
    for (int i = t; i < (NCLS * HID) / 4; i += 256) d4[i] = s4[i];
  }
  __syncthreads();
  const int w = t >> 6, l = t & 63;
  const int row = blockIdx.x * 4 + w;

  float r[16];
#pragma unroll
  for (int jj = 0; jj < 4; ++jj) {
    floatv4 bb = *(const floatv4*)&b1[jj * 256 + l * 4];
    float s[4] = {bb[0], bb[1], bb[2], bb[3]};
#pragma unroll
    for (int p = 0; p < KS; ++p) {
      const half_t* cp = Cb + (size_t)p * ((size_t)NBS * HID) + (size_t)row * HID;
      halfv4 u = *(const halfv4*)&cp[jj * 256 + l * 4];
#pragma unroll
      for (int q = 0; q < 4; ++q) s[q] += (float)u[q];
    }
#pragma unroll
    for (int q = 0; q < 4; ++q) r[jj * 4 + q] = s[q] > 0.f ? s[q] : 0.f;
  }
  float lg[10];
#pragma unroll
  for (int c = 0; c < NCLS; ++c) {
    float p = 0.f;
#pragma unroll
    for (int jj = 0; jj < 4; ++jj) {
      floatv4 wv = *(const floatv4*)&w2s[c * HID + jj * 256 + l * 4];
      p += r[jj * 4 + 0] * wv[0] + r[jj * 4 + 1] * wv[1] +
           r[jj * 4 + 2] * wv[2] + r[jj * 4 + 3] * wv[3];
    }
#pragma unroll
    for (int off = 32; off >= 1; off >>= 1) p += __shfl_xor(p, off);
    lg[c] = p + b2[c];
  }
  float mx = lg[0];
#pragma unroll
  for (int c = 1; c < NCLS; ++c) mx = fmaxf(mx, lg[c]);
  float sum = 0.f;
#pragma unroll
  for (int c = 0; c < NCLS; ++c) { lg[c] = __expf(lg[c] - mx); sum += lg[c]; }
  const float inv = 1.f / sum;
  float myv = 0.f;
#pragma unroll
  for (int c = 0; c < NCLS; ++c) myv = (l == c) ? lg[c] * inv : myv;
  if (l < NCLS) out[(size_t)row * NCLS + l] = myv;
}

// ---------------------------------------------------------------------------
extern "C" void kernel_launch(void* const* d_in, const int* in_sizes, int n_in,
                              void* d_out, int out_size, void* d_ws, size_t ws_size,
                              hipStream_t stream) {
  (void)in_sizes; (void)n_in; (void)out_size; (void)ws_size;
  const float* x  = (const float*)d_in[0];
  const int*   ei = (const int*)d_in[1];
  const float* gw = (const float*)d_in[2];
  const float* gb = (const float*)d_in[3];
  const float* w1 = (const float*)d_in[4];
  const float* b1 = (const float*)d_in[5];
  const float* w2 = (const float*)d_in[6];
  const float* b2 = (const float*)d_in[7];
  float* out = (float*)d_out;

  char* ws = (char*)d_ws;
  half_t* H    = (half_t*)(ws);                        // 32 MB
  half_t* C    = (half_t*)(ws + 33554432);             // KS x 8 MB = 32 MB
  half_t* w1p  = (half_t*)(ws + 67108864);             //  8 MB
  half_t* gw16 = (half_t*)(ws + 75497472);             // 32 KB

  prep_cvt <<<dim3(4112),    dim3(256), 0, stream>>>(w1, w1p, gw, gw16);
  gin_fused<<<dim3(NBS / 4), dim3(256), 0, stream>>>(x, ei, gw16, gb, H);
  lin1_gemm<<<dim3(16 * 4 * KS), dim3(512), 0, stream>>>(H, w1p, C);
  head     <<<dim3(NBS / 4), dim3(256), 0, stream>>>(C, b1, w2, b2, out);
}

// Round 9
// 96.858 us; speedup vs baseline: 1.2555x; 1.0217x over previous
//
#include <hip/hip_runtime.h>

typedef _Float16 half_t;
typedef _Float16 halfv8 __attribute__((ext_vector_type(8)));
typedef _Float16 halfv4 __attribute__((ext_vector_type(4)));
typedef float    floatv4 __attribute__((ext_vector_type(4)));
typedef unsigned int uint;
typedef uint uintv4 __attribute__((ext_vector_type(4)));

#define NODES 32
#define FIN   128
#define EPG   512
#define NBS   4096
#define ETOT  (NBS*EPG)
#define HID   1024
#define KDIM  4096          // FIN*NODES
#define NCLS  10
#define YP    36            // pitch (halves) for Z^T / H^T bounce

// lin1 GEMM geometry (r4-proven: 128B rows, XOR-8, 0 conflicts)
#define BM 256
#define BN 256
#define BK 64
#define KS 4
#define KSLEN (KDIM/KS)  // 1024
#define NT (KSLEN/BK)    // 16 K-tiles

#define GLDS16(g, l)                                                        \
  __builtin_amdgcn_global_load_lds(                                         \
      (const __attribute__((address_space(1))) unsigned int*)(g),           \
      (__attribute__((address_space(3))) unsigned int*)(l), 16, 0, 0)

// ---------------------------------------------------------------------------
// prep: pure fp32->fp16 casts (H layout [g][f*32+node] matches original w1).
__global__ __launch_bounds__(256) void prep_cvt(const float* __restrict__ w1,
                                                half_t* __restrict__ w1p,
                                                const float* __restrict__ gw,
                                                half_t* __restrict__ gw16) {
  const size_t q = (size_t)blockIdx.x * 256 + threadIdx.x;  // 1052672 quads
  const float* s;
  half_t* d;
  size_t off;
  if (q < 1048576) { s = w1; d = w1p; off = q; }
  else             { s = gw; d = gw16; off = q - 1048576; }
  floatv4 v = *(const floatv4*)(s + off * 4);
  halfv4 h = {(half_t)v[0], (half_t)v[1], (half_t)v[2], (half_t)v[3]};
  *(halfv4*)(d + off * 4) = h;
}

// ---------------------------------------------------------------------------
// gin_fused v5: H_g = relu((I + C_g) @ (x_g @ W^T) + b), stored [g][f*32+m].
// Delta vs r7-v3 (passed): x ingested via 16 COALESCED global_load_lds
// (1KB/instr, source-side XOR-8 swizzle) instead of per-lane 16-row gathers.
// Per-wave 16KB LDS buffer triple-used: x-stage -> Z^T bounce -> H^T repack.
__global__ __launch_bounds__(256, 2) void gin_fused(
    const float* __restrict__ x, const int* __restrict__ ei,
    const half_t* __restrict__ gw16, const float* __restrict__ gb,
    half_t* __restrict__ H) {
  __shared__ __attribute__((aligned(16))) half_t buf[4][8192];  // 64 KB
  __shared__ uint cnt[4][512];                                  //  8 KB

  const int t = threadIdx.x, w = t >> 6, l = t & 63;
  const int lr = l & 15, lk = l >> 4;
  const int g = blockIdx.x * 4 + w;
  const float* xg = x + (size_t)g * (NODES * FIN);
  half_t* bw = buf[w];

  // (a) stage x (32x128 fp32 = 16KB) coalesced; LDS[r][c] = G[r][swz(c)]
  // where swz XORs the low-3 chunk bits with (r&7). 16 instrs, 1KB each.
#pragma unroll
  for (int i = 0; i < 16; ++i) {
    const int p = i * 64 + l;              // 16B-chunk position (0..1023)
    const int r = p >> 5, c = p & 31;      // row (0..31), chunk-in-row
    const int cs = (c & ~7) | ((c & 7) ^ (r & 7));
    GLDS16(xg + r * FIN + cs * 4, bw + (size_t)p * 8);
  }

  // (b) edges (contiguous per graph; local id = idx & 31)
  const int* sp = ei + (size_t)g * EPG;
  const int* dp = ei + (size_t)ETOT + (size_t)g * EPG;
  uintv4 s0 = *(const uintv4*)(sp + l * 8);
  uintv4 s1 = *(const uintv4*)(sp + l * 8 + 4);
  uintv4 d0 = *(const uintv4*)(dp + l * 8);
  uintv4 d1 = *(const uintv4*)(dp + l * 8 + 4);

  // (c) wave-private histogram: cnt16[dst*32+src] += 1 (packed u16 pairs)
  {
    uintv4* c4 = (uintv4*)cnt[w];
    uintv4 z = {0, 0, 0, 0};
    c4[l] = z;
    c4[l + 64] = z;
  }
#pragma unroll
  for (int q = 0; q < 4; ++q) {
    uint p0 = (d0[q] & 31) * 32 + (s0[q] & 31);
    atomicAdd(&cnt[w][p0 >> 1], 1u << ((p0 & 1) * 16));
    uint p1 = (d1[q] & 31) * 32 + (s1[q] & 31);
    atomicAdd(&cnt[w][p1 >> 1], 1u << ((p1 & 1) * 16));
  }

  // (d) x staged (own-wave loads) -> read fragments from LDS, convert fp16
  asm volatile("s_waitcnt vmcnt(0)" ::: "memory");
  halfv8 af[2][4];
#pragma unroll
  for (int mt = 0; mt < 2; ++mt)
#pragma unroll
    for (int kk = 0; kk < 4; ++kk) {
      const int rr = mt * 16 + lr;
      const int c0 = kk * 8 + ((lk * 2 + 0) ^ (lr & 7));
      const int c1 = kk * 8 + ((lk * 2 + 1) ^ (lr & 7));
      floatv4 u = *(const floatv4*)&bw[(rr * 32 + c0) * 8];
      floatv4 v = *(const floatv4*)&bw[(rr * 32 + c1) * 8];
      halfv8 h;
#pragma unroll
      for (int q = 0; q < 4; ++q) {
        h[q]     = (half_t)u[q];
        h[q + 4] = (half_t)v[q];
      }
      af[mt][kk] = h;
    }

  // (e) MFMA1: Z[j][o] = sum_f x[j][f] W[o][f]; W frags from global (L1/L2)
  floatv4 acc[2][8] = {};
#pragma unroll
  for (int kk = 0; kk < 4; ++kk) {
    halfv8 bfk[8];
#pragma unroll
    for (int nt = 0; nt < 8; ++nt)
      bfk[nt] = *(const halfv8*)(gw16 + (nt * 16 + lr) * FIN + kk * 32 + lk * 8);
#pragma unroll
    for (int nt = 0; nt < 8; ++nt)
#pragma unroll
      for (int mt = 0; mt < 2; ++mt)
        acc[mt][nt] = __builtin_amdgcn_mfma_f32_16x16x32_f16(af[mt][kk], bfk[nt],
                                                             acc[mt][nt], 0, 0, 0);
  }
  __builtin_amdgcn_sched_barrier(0);   // all x-frag reads precede Z^T writes

  // (f) bounce Z^T into same buffer: Yt[o][j] (x data now dead)
#pragma unroll
  for (int mt = 0; mt < 2; ++mt)
#pragma unroll
    for (int nt = 0; nt < 8; ++nt) {
      halfv4 h = {(half_t)acc[mt][nt][0], (half_t)acc[mt][nt][1],
                  (half_t)acc[mt][nt][2], (half_t)acc[mt][nt][3]};
      *(halfv4*)&bw[(nt * 16 + lr) * YP + mt * 16 + lk * 4] = h;
    }

  // (g) M' = I + C fragments from histogram
  const unsigned short* c16 = (const unsigned short*)cnt[w];
  halfv8 am[2];
#pragma unroll
  for (int mt = 0; mt < 2; ++mt) {
    const int i = mt * 16 + lr;
#pragma unroll
    for (int q = 0; q < 8; ++q) {
      const int j = lk * 8 + q;
      float c = (float)c16[i * 32 + j] + ((j == i) ? 1.f : 0.f);
      am[mt][q] = (half_t)c;
    }
  }

  // (h) MFMA2: H[i][o] = sum_j M'[i][j] Z[j][o]
  floatv4 acc2[2][8] = {};
#pragma unroll
  for (int nt = 0; nt < 8; ++nt) {
    halfv8 bf = *(const halfv8*)&bw[(nt * 16 + lr) * YP + lk * 8];
#pragma unroll
    for (int mt = 0; mt < 2; ++mt)
      acc2[mt][nt] = __builtin_amdgcn_mfma_f32_16x16x32_f16(am[mt], bf,
                                                            acc2[mt][nt], 0, 0, 0);
  }
  __builtin_amdgcn_sched_barrier(0);   // keep H^T writes below all Z^T reads

  // (i) bias + relu; overwrite buffer with H^T[o][m]
#pragma unroll
  for (int nt = 0; nt < 8; ++nt) {
    const float bias = gb[nt * 16 + lr];
#pragma unroll
    for (int mt = 0; mt < 2; ++mt) {
      halfv4 h;
#pragma unroll
      for (int q = 0; q < 4; ++q) {
        const float v = acc2[mt][nt][q] + bias;
        h[q] = (half_t)(v > 0.f ? v : 0.f);
      }
      *(halfv4*)&bw[(nt * 16 + lr) * YP + mt * 16 + lk * 4] = h;
    }
  }
  __builtin_amdgcn_sched_barrier(0);

  // (j) linear readback -> fat coalesced stores: H[g][o*32+m], 1KB/instr
  half_t* Hg = H + (size_t)g * KDIM;
#pragma unroll
  for (int c = 0; c < 8; ++c) {
    const int ch = c * 64 + l;          // 512 chunks of 8 halves
    const int o = ch >> 2, m0 = (ch & 3) * 8;
    halfv8 v = *(const halfv8*)&bw[o * YP + m0];
    *(halfv8*)(Hg + ch * 8) = v;
  }
}

// ---------------------------------------------------------------------------
// lin1 GEMM (r4-proven): 256x256 tile, BK=64 (128B rows), 8 waves, split-K=4,
// XOR-8 chunk swizzle (0 conflicts), de-lockstepped 2-barrier K-loop,
// counted vmcnt(8) with 1-tile lookahead.
__global__ __launch_bounds__(512, 2) void lin1_gemm(
    const half_t* __restrict__ A, const half_t* __restrict__ B,
    half_t* __restrict__ Cbase) {
  __shared__ __attribute__((aligned(16))) half_t As[2][BM * BK];  // 64 KB
  __shared__ __attribute__((aligned(16))) half_t Bs[2][BN * BK];  // 64 KB

  const int t = threadIdx.x;
  const int orig = blockIdx.x;
  const int wg = (orig & 7) * 32 + (orig >> 3);    // bijective XCD swizzle
  const int mt = wg & 15, rest = wg >> 4;
  const int nt_ = rest & 3, ks = rest >> 2;
  const int m0 = mt * BM, n0 = nt_ * BN, k0 = ks * KSLEN;

  const half_t* gA[4];
  const half_t* gB[4];
#pragma unroll
  for (int j = 0; j < 4; ++j) {
    const int L = t + j * 512;
    const int r = L >> 3;
    const int c = (L & 7) ^ (r & 7);
    gA[j] = A + (size_t)(m0 + r) * KDIM + k0 + c * 8;
    gB[j] = B + (size_t)(n0 + r) * KDIM + k0 + c * 8;
  }

#define STAGE(buf, koff)                                                    \
  {                                                                         \
    _Pragma("unroll")                                                       \
    for (int j = 0; j < 4; ++j)                                             \
      GLDS16(gA[j] + (koff), &As[buf][(t + j * 512) * 8]);                  \
    _Pragma("unroll")                                                       \
    for (int j = 0; j < 4; ++j)                                             \
      GLDS16(gB[j] + (koff), &Bs[buf][(t + j * 512) * 8]);                  \
  }

  const int w = t >> 6, l = t & 63, lr = l & 15, lk = l >> 4;
  const int wm = (w >> 2) * 128, wn = (w & 3) * 64;

  floatv4 acc[8][4] = {};

  STAGE(0, 0)
  STAGE(1, BK)
  asm volatile("s_waitcnt vmcnt(8)" ::: "memory");
  __builtin_amdgcn_s_barrier();

  for (int kt = 0; kt < NT; ++kt) {
    const int cur = kt & 1;
    const half_t* as = As[cur];
    const half_t* bs = Bs[cur];
#pragma unroll
    for (int ksb = 0; ksb < 2; ++ksb) {
      halfv8 bf[4], af[8];
#pragma unroll
      for (int nf = 0; nf < 4; ++nf) {
        const int row = wn + nf * 16 + lr;
        const int ch = (ksb * 4 + lk) ^ (row & 7);
        bf[nf] = *(const halfv8*)&bs[row * BK + ch * 8];
      }
#pragma unroll
      for (int mf = 0; mf < 8; ++mf) {
        const int row = wm + mf * 16 + lr;
        const int ch = (ksb * 4 + lk) ^ (row & 7);
        af[mf] = *(const halfv8*)&as[row * BK + ch * 8];
      }
      __builtin_amdgcn_s_setprio(1);
#pragma unroll
      for (int mf = 0; mf < 8; ++mf)
#pragma unroll
        for (int nf = 0; nf < 4; ++nf)
          acc[mf][nf] = __builtin_amdgcn_mfma_f32_16x16x32_f16(
              af[mf], bf[nf], acc[mf][nf], 0, 0, 0);
      __builtin_amdgcn_s_setprio(0);
    }
    __builtin_amdgcn_s_barrier();
    const int src = (kt + 2 < NT) ? (kt + 2) : 0;  // dummy keeps vmcnt uniform
    STAGE(cur, src * BK)
    asm volatile("s_waitcnt vmcnt(8)" ::: "memory");
    __builtin_amdgcn_s_barrier();
  }

  half_t* C = Cbase + (size_t)ks * ((size_t)NBS * HID);
#pragma unroll
  for (int mf = 0; mf < 8; ++mf)
#pragma unroll
    for (int nf = 0; nf < 4; ++nf) {
      const int n = n0 + wn + nf * 16 + lr;
#pragma unroll
      for (int q = 0; q < 4; ++q) {
        const int m = m0 + wm + mf * 16 + lk * 4 + q;
        C[(size_t)m * HID + n] = (half_t)acc[mf][nf][q];
      }
    }
#undef STAGE
}

// ---------------------------------------------------------------------------
// head: hidden = relu(sum_ks C[ks] + b1); logits = hidden @ w2^T + b2; softmax
__global__ __launch_bounds__(256) void head(
    const half_t* __restrict__ Cb, const float* __restrict__ b1,
    const float* __restrict__ w2, const float* __restrict__ b2,
    float* __restrict__ out) {
  __shared__ __attribute__((aligned(16))) float w2s[NCLS * HID];
  const int t = threadIdx.x;
  {
    const floatv4* s4 = (const floatv4*)w2;
    floatv4* d4 = (floatv4*)w2s;
    for (int i = t; i < (NCLS * HID) / 4; i += 256) d4[i] = s4[i];
  }
  __syncthreads();
  const int w = t >> 6, l = t & 63;
  const int row = blockIdx.x * 4 + w;

  float r[16];
#pragma unroll
  for (int jj = 0; jj < 4; ++jj) {
    floatv4 bb = *(const floatv4*)&b1[jj * 256 + l * 4];
    float s[4] = {bb[0], bb[1], bb[2], bb[3]};
#pragma unroll
    for (int p = 0; p < KS; ++p) {
      const half_t* cp = Cb + (size_t)p * ((size_t)NBS * HID) + (size_t)row * HID;
      halfv4 u = *(const halfv4*)&cp[jj * 256 + l * 4];
#pragma unroll
      for (int q = 0; q < 4; ++q) s[q] += (float)u[q];
    }
#pragma unroll
    for (int q = 0; q < 4; ++q) r[jj * 4 + q] = s[q] > 0.f ? s[q] : 0.f;
  }
  float lg[10];
#pragma unroll
  for (int c = 0; c < NCLS; ++c) {
    float p = 0.f;
#pragma unroll
    for (int jj = 0; jj < 4; ++jj) {
      floatv4 wv = *(const floatv4*)&w2s[c * HID + jj * 256 + l * 4];
      p += r[jj * 4 + 0] * wv[0] + r[jj * 4 + 1] * wv[1] +
           r[jj * 4 + 2] * wv[2] + r[jj * 4 + 3] * wv[3];
    }
#pragma unroll
    for (int off = 32; off >= 1; off >>= 1) p += __shfl_xor(p, off);
    lg[c] = p + b2[c];
  }
  float mx = lg[0];
#pragma unroll
  for (int c = 1; c < NCLS; ++c) mx = fmaxf(mx, lg[c]);
  float sum = 0.f;
#pragma unroll
  for (int c = 0; c < NCLS; ++c) { lg[c] = __expf(lg[c] - mx); sum += lg[c]; }
  const float inv = 1.f / sum;
  float myv = 0.f;
#pragma unroll
  for (int c = 0; c < NCLS; ++c) myv = (l == c) ? lg[c] * inv : myv;
  if (l < NCLS) out[(size_t)row * NCLS + l] = myv;
}

// ---------------------------------------------------------------------------
extern "C" void kernel_launch(void* const* d_in, const int* in_sizes, int n_in,
                              void* d_out, int out_size, void* d_ws, size_t ws_size,
                              hipStream_t stream) {
  (void)in_sizes; (void)n_in; (void)out_size; (void)ws_size;
  const float* x  = (const float*)d_in[0];
  const int*   ei = (const int*)d_in[1];
  const float* gw = (const float*)d_in[2];
  const float* gb = (const float*)d_in[3];
  const float* w1 = (const float*)d_in[4];
  const float* b1 = (const float*)d_in[5];
  const float* w2 = (const float*)d_in[6];
  const float* b2 = (const float*)d_in[7];
  float* out = (float*)d_out;

  char* ws = (char*)d_ws;
  half_t* H    = (half_t*)(ws);                        // 32 MB
  half_t* C    = (half_t*)(ws + 33554432);             // KS x 8 MB = 32 MB
  half_t* w1p  = (half_t*)(ws + 67108864);             //  8 MB
  half_t* gw16 = (half_t*)(ws + 75497472);             // 32 KB

  prep_cvt <<<dim3(4112),    dim3(256), 0, stream>>>(w1, w1p, gw, gw16);
  gin_fused<<<dim3(NBS / 4), dim3(256), 0, stream>>>(x, ei, gw16, gb, H);
  lin1_gemm<<<dim3(16 * 4 * KS), dim3(512), 0, stream>>>(H, w1p, C);
  head     <<<dim3(NBS / 4), dim3(256), 0, stream>>>(C, b1, w2, b2, out);
}

// Round 10
// 86.724 us; speedup vs baseline: 1.4022x; 1.1169x over previous
//
#include <hip/hip_runtime.h>

typedef _Float16 half_t;
typedef _Float16 halfv8 __attribute__((ext_vector_type(8)));
typedef _Float16 halfv4 __attribute__((ext_vector_type(4)));
typedef float    floatv4 __attribute__((ext_vector_type(4)));
typedef unsigned int uint;
typedef uint uintv4 __attribute__((ext_vector_type(4)));

#define NODES 32
#define FIN   128
#define EPG   512
#define NBS   4096
#define ETOT  (NBS*EPG)
#define HID   1024
#define KDIM  4096          // FIN*NODES
#define NCLS  10
#define YP    36            // pitch (halves) for Z^T / H^T bounce
#define WP    140           // pitch (halves) for W in LDS (bank stride 6 -> 2-way max)

// lin1 GEMM geometry (proven: 128B rows, XOR-8, 0 conflicts)
#define BM 256
#define BN 256
#define BK 64
#define KS 4
#define KSLEN (KDIM/KS)  // 1024
#define NT (KSLEN/BK)    // 16 K-tiles

#define GLDS16(g, l)                                                        \
  __builtin_amdgcn_global_load_lds(                                         \
      (const __attribute__((address_space(1))) unsigned int*)(g),           \
      (__attribute__((address_space(3))) unsigned int*)(l), 16, 0, 0)

// ---------------------------------------------------------------------------
// prep: pure fp32->fp16 casts (H layout [g][f*32+node] matches original w1).
__global__ __launch_bounds__(256) void prep_cvt(const float* __restrict__ w1,
                                                half_t* __restrict__ w1p,
                                                const float* __restrict__ gw,
                                                half_t* __restrict__ gw16) {
  const size_t q = (size_t)blockIdx.x * 256 + threadIdx.x;  // 1052672 quads
  const float* s;
  half_t* d;
  size_t off;
  if (q < 1048576) { s = w1; d = w1p; off = q; }
  else             { s = gw; d = gw16; off = q - 1048576; }
  floatv4 v = *(const floatv4*)(s + off * 4);
  halfv4 h = {(half_t)v[0], (half_t)v[1], (half_t)v[2], (half_t)v[3]};
  *(halfv4*)(d + off * 4) = h;
}

// ---------------------------------------------------------------------------
// gin_fused v6: H_g = relu((I + C_g) @ (x_g @ W^T) + b), stored [g][o*32+m].
// Single delta vs r9: W fragments come from block-staged LDS (coalesced
// one-time stage) instead of per-wave 16-segment global gathers.
__global__ __launch_bounds__(256, 2) void gin_fused(
    const float* __restrict__ x, const int* __restrict__ ei,
    const half_t* __restrict__ gw16, const float* __restrict__ gb,
    half_t* __restrict__ H) {
  __shared__ __attribute__((aligned(16))) half_t Ws[FIN * WP];     // 35840 B
  __shared__ __attribute__((aligned(16))) half_t Yt[4][FIN * YP];  // 36864 B
  __shared__ uint cnt[4][512];                                     //  8192 B
  // total 80,896 B -> 2 blocks/CU

  const int t = threadIdx.x, w = t >> 6, l = t & 63;
  const int lr = l & 15, lk = l >> 4;
  const int g = blockIdx.x * 4 + w;

  // (a) x tile (32x128 fp32) -> registers, batch-issued
  const float* xg = x + (size_t)g * (NODES * FIN);
  floatv4 xr[2][4][2];
#pragma unroll
  for (int mt = 0; mt < 2; ++mt)
#pragma unroll
    for (int kk = 0; kk < 4; ++kk) {
      const float* p = xg + (mt * 16 + lr) * FIN + kk * 32 + lk * 8;
      xr[mt][kk][0] = *(const floatv4*)p;
      xr[mt][kk][1] = *(const floatv4*)(p + 4);
    }

  // (b) stage W into LDS, coalesced halfv8 chunks (one time per block)
  {
    const halfv8* gsrc = (const halfv8*)gw16;
#pragma unroll
    for (int i = 0; i < 8; ++i) {
      const int c = i * 256 + t;          // 2048 chunks
      const int o = c >> 4, f8 = c & 15;
      *(halfv8*)&Ws[o * WP + f8 * 8] = gsrc[c];
    }
  }

  // (c) edges (contiguous per graph; local id = idx & 31)
  const int* sp = ei + (size_t)g * EPG;
  const int* dp = ei + (size_t)ETOT + (size_t)g * EPG;
  uintv4 s0 = *(const uintv4*)(sp + l * 8);
  uintv4 s1 = *(const uintv4*)(sp + l * 8 + 4);
  uintv4 d0 = *(const uintv4*)(dp + l * 8);
  uintv4 d1 = *(const uintv4*)(dp + l * 8 + 4);

  // (d) wave-private histogram: cnt16[dst*32+src] += 1 (packed u16 pairs)
  {
    uintv4* c4 = (uintv4*)cnt[w];
    uintv4 z = {0, 0, 0, 0};
    c4[l] = z;
    c4[l + 64] = z;
  }
#pragma unroll
  for (int q = 0; q < 4; ++q) {
    uint p0 = (d0[q] & 31) * 32 + (s0[q] & 31);
    atomicAdd(&cnt[w][p0 >> 1], 1u << ((p0 & 1) * 16));
    uint p1 = (d1[q] & 31) * 32 + (s1[q] & 31);
    atomicAdd(&cnt[w][p1 >> 1], 1u << ((p1 & 1) * 16));
  }

  // (e) x -> fp16 A-fragments
  halfv8 af[2][4];
#pragma unroll
  for (int mt = 0; mt < 2; ++mt)
#pragma unroll
    for (int kk = 0; kk < 4; ++kk) {
      halfv8 h;
#pragma unroll
      for (int q = 0; q < 4; ++q) {
        h[q]     = (half_t)xr[mt][kk][0][q];
        h[q + 4] = (half_t)xr[mt][kk][1][q];
      }
      af[mt][kk] = h;
    }

  __syncthreads();   // Ws staged (cross-wave)

  // (f) MFMA1: Z[j][o] = sum_f x[j][f] W[o][f]; W frags from LDS
  floatv4 acc[2][8] = {};
#pragma unroll
  for (int kk = 0; kk < 4; ++kk) {
    halfv8 bfk[8];
#pragma unroll
    for (int nt = 0; nt < 8; ++nt)
      bfk[nt] = *(const halfv8*)&Ws[(nt * 16 + lr) * WP + kk * 32 + lk * 8];
#pragma unroll
    for (int nt = 0; nt < 8; ++nt)
#pragma unroll
      for (int mt = 0; mt < 2; ++mt)
        acc[mt][nt] = __builtin_amdgcn_mfma_f32_16x16x32_f16(af[mt][kk], bfk[nt],
                                                             acc[mt][nt], 0, 0, 0);
  }
  __builtin_amdgcn_sched_barrier(0);

  // (g) bounce Z^T into this wave's LDS: Yt[o][j]
  half_t* yw = Yt[w];
#pragma unroll
  for (int mt = 0; mt < 2; ++mt)
#pragma unroll
    for (int nt = 0; nt < 8; ++nt) {
      halfv4 h = {(half_t)acc[mt][nt][0], (half_t)acc[mt][nt][1],
                  (half_t)acc[mt][nt][2], (half_t)acc[mt][nt][3]};
      *(halfv4*)&yw[(nt * 16 + lr) * YP + mt * 16 + lk * 4] = h;
    }

  // (h) M' = I + C fragments from histogram
  const unsigned short* c16 = (const unsigned short*)cnt[w];
  halfv8 am[2];
#pragma unroll
  for (int mt = 0; mt < 2; ++mt) {
    const int i = mt * 16 + lr;
#pragma unroll
    for (int q = 0; q < 8; ++q) {
      const int j = lk * 8 + q;
      float c = (float)c16[i * 32 + j] + ((j == i) ? 1.f : 0.f);
      am[mt][q] = (half_t)c;
    }
  }

  // (i) MFMA2: H[i][o] = sum_j M'[i][j] Z[j][o]
  floatv4 acc2[2][8] = {};
#pragma unroll
  for (int nt = 0; nt < 8; ++nt) {
    halfv8 bf = *(const halfv8*)&yw[(nt * 16 + lr) * YP + lk * 8];
#pragma unroll
    for (int mt = 0; mt < 2; ++mt)
      acc2[mt][nt] = __builtin_amdgcn_mfma_f32_16x16x32_f16(am[mt], bf,
                                                            acc2[mt][nt], 0, 0, 0);
  }
  __builtin_amdgcn_sched_barrier(0);   // keep H^T writes below all Z^T reads

  // (j) bias + relu; overwrite buffer with H^T[o][m]
#pragma unroll
  for (int nt = 0; nt < 8; ++nt) {
    const float bias = gb[nt * 16 + lr];
#pragma unroll
    for (int mt = 0; mt < 2; ++mt) {
      halfv4 h;
#pragma unroll
      for (int q = 0; q < 4; ++q) {
        const float v = acc2[mt][nt][q] + bias;
        h[q] = (half_t)(v > 0.f ? v : 0.f);
      }
      *(halfv4*)&yw[(nt * 16 + lr) * YP + mt * 16 + lk * 4] = h;
    }
  }
  __builtin_amdgcn_sched_barrier(0);

  // (k) linear readback -> fat coalesced stores: H[g][o*32+m], 1KB/instr
  half_t* Hg = H + (size_t)g * KDIM;
#pragma unroll
  for (int c = 0; c < 8; ++c) {
    const int ch = c * 64 + l;          // 512 chunks of 8 halves
    const int o = ch >> 2, m0 = (ch & 3) * 8;
    halfv8 v = *(const halfv8*)&yw[o * YP + m0];
    *(halfv8*)(Hg + ch * 8) = v;
  }
}

// ---------------------------------------------------------------------------
// lin1 GEMM (proven r4/r9): 256x256 tile, BK=64 (128B rows), 8 waves,
// split-K=4, XOR-8 chunk swizzle (0 conflicts), 2-barrier K-loop,
// counted vmcnt(8) with 1-tile lookahead.
__global__ __launch_bounds__(512, 2) void lin1_gemm(
    const half_t* __restrict__ A, const half_t* __restrict__ B,
    half_t* __restrict__ Cbase) {
  __shared__ __attribute__((aligned(16))) half_t As[2][BM * BK];  // 64 KB
  __shared__ __attribute__((aligned(16))) half_t Bs[2][BN * BK];  // 64 KB

  const int t = threadIdx.x;
  const int orig = blockIdx.x;
  const int wg = (orig & 7) * 32 + (orig >> 3);    // bijective XCD swizzle
  const int mt = wg & 15, rest = wg >> 4;
  const int nt_ = rest & 3, ks = rest >> 2;
  const int m0 = mt * BM, n0 = nt_ * BN, k0 = ks * KSLEN;

  const half_t* gA[4];
  const half_t* gB[4];
#pragma unroll
  for (int j = 0; j < 4; ++j) {
    const int L = t + j * 512;
    const int r = L >> 3;
    const int c = (L & 7) ^ (r & 7);
    gA[j] = A + (size_t)(m0 + r) * KDIM + k0 + c * 8;
    gB[j] = B + (size_t)(n0 + r) * KDIM + k0 + c * 8;
  }

#define STAGE(buf, koff)                                                    \
  {                                                                         \
    _Pragma("unroll")                                                       \
    for (int j = 0; j < 4; ++j)                                             \
      GLDS16(gA[j] + (koff), &As[buf][(t + j * 512) * 8]);                  \
    _Pragma("unroll")                                                       \
    for (int j = 0; j < 4; ++j)                                             \
      GLDS16(gB[j] + (koff), &Bs[buf][(t + j * 512) * 8]);                  \
  }

  const int w = t >> 6, l = t & 63, lr = l & 15, lk = l >> 4;
  const int wm = (w >> 2) * 128, wn = (w & 3) * 64;

  floatv4 acc[8][4] = {};

  STAGE(0, 0)
  STAGE(1, BK)
  asm volatile("s_waitcnt vmcnt(8)" ::: "memory");
  __builtin_amdgcn_s_barrier();

  for (int kt = 0; kt < NT; ++kt) {
    const int cur = kt & 1;
    const half_t* as = As[cur];
    const half_t* bs = Bs[cur];
#pragma unroll
    for (int ksb = 0; ksb < 2; ++ksb) {
      halfv8 bf[4], af[8];
#pragma unroll
      for (int nf = 0; nf < 4; ++nf) {
        const int row = wn + nf * 16 + lr;
        const int ch = (ksb * 4 + lk) ^ (row & 7);
        bf[nf] = *(const halfv8*)&bs[row * BK + ch * 8];
      }
#pragma unroll
      for (int mf = 0; mf < 8; ++mf) {
        const int row = wm + mf * 16 + lr;
        const int ch = (ksb * 4 + lk) ^ (row & 7);
        af[mf] = *(const halfv8*)&as[row * BK + ch * 8];
      }
      __builtin_amdgcn_s_setprio(1);
#pragma unroll
      for (int mf = 0; mf < 8; ++mf)
#pragma unroll
        for (int nf = 0; nf < 4; ++nf)
          acc[mf][nf] = __builtin_amdgcn_mfma_f32_16x16x32_f16(
              af[mf], bf[nf], acc[mf][nf], 0, 0, 0);
      __builtin_amdgcn_s_setprio(0);
    }
    __builtin_amdgcn_s_barrier();
    const int src = (kt + 2 < NT) ? (kt + 2) : 0;  // dummy keeps vmcnt uniform
    STAGE(cur, src * BK)
    asm volatile("s_waitcnt vmcnt(8)" ::: "memory");
    __builtin_amdgcn_s_barrier();
  }

  half_t* C = Cbase + (size_t)ks * ((size_t)NBS * HID);
#pragma unroll
  for (int mf = 0; mf < 8; ++mf)
#pragma unroll
    for (int nf = 0; nf < 4; ++nf) {
      const int n = n0 + wn + nf * 16 + lr;
#pragma unroll
      for (int q = 0; q < 4; ++q) {
        const int m = m0 + wm + mf * 16 + lk * 4 + q;
        C[(size_t)m * HID + n] = (half_t)acc[mf][nf][q];
      }
    }
#undef STAGE
}

// ---------------------------------------------------------------------------
// head: hidden = relu(sum_ks C[ks] + b1); logits = hidden @ w2^T + b2; softmax
__global__ __launch_bounds__(256) void head(
    const half_t* __restrict__ Cb, const float* __restrict__ b1,
    const float* __restrict__ w2, const float* __restrict__ b2,
    float* __restrict__ out) {
  __shared__ __attribute__((aligned(16))) float w2s[NCLS * HID];
  const int t = threadIdx.x;
  {
    const floatv4* s4 = (const floatv4*)w2;
    floatv4* d4 = (floatv4*)w2s;
    for (int i = t; i < (NCLS * HID) / 4; i += 256) d4[i] = s4[i];
  }
  __syncthreads();
  const int w = t >> 6, l = t & 63;
  const int row = blockIdx.x * 4 + w;

  float r[16];
#pragma unroll
  for (int jj = 0; jj < 4; ++jj) {
    floatv4 bb = *(const floatv4*)&b1[jj * 256 + l * 4];
    float s[4] = {bb[0], bb[1], bb[2], bb[3]};
#pragma unroll
    for (int p = 0; p < KS; ++p) {
      const half_t* cp = Cb + (size_t)p * ((size_t)NBS * HID) + (size_t)row * HID;
      halfv4 u = *(const halfv4*)&cp[jj * 256 + l * 4];
#pragma unroll
      for (int q = 0; q < 4; ++q) s[q] += (float)u[q];
    }
#pragma unroll
    for (int q = 0; q < 4; ++q) r[jj * 4 + q] = s[q] > 0.f ? s[q] : 0.f;
  }
  float lg[10];
#pragma unroll
  for (int c = 0; c < NCLS; ++c) {
    float p = 0.f;
#pragma unroll
    for (int jj = 0; jj < 4; ++jj) {
      floatv4 wv = *(const floatv4*)&w2s[c * HID + jj * 256 + l * 4];
      p += r[jj * 4 + 0] * wv[0] + r[jj * 4 + 1] * wv[1] +
           r[jj * 4 + 2] * wv[2] + r[jj * 4 + 3] * wv[3];
    }
#pragma unroll
    for (int off = 32; off >= 1; off >>= 1) p += __shfl_xor(p, off);
    lg[c] = p + b2[c];
  }
  float mx = lg[0];
#pragma unroll
  for (int c = 1; c < NCLS; ++c) mx = fmaxf(mx, lg[c]);
  float sum = 0.f;
#pragma unroll
  for (int c = 0; c < NCLS; ++c) { lg[c] = __expf(lg[c] - mx); sum += lg[c]; }
  const float inv = 1.f / sum;
  float myv = 0.f;
#pragma unroll
  for (int c = 0; c < NCLS; ++c) myv = (l == c) ? lg[c] * inv : myv;
  if (l < NCLS) out[(size_t)row * NCLS + l] = myv;
}

// ---------------------------------------------------------------------------
extern "C" void kernel_launch(void* const* d_in, const int* in_sizes, int n_in,
                              void* d_out, int out_size, void* d_ws, size_t ws_size,
                              hipStream_t stream) {
  (void)in_sizes; (void)n_in; (void)out_size; (void)ws_size;
  const float* x  = (const float*)d_in[0];
  const int*   ei = (const int*)d_in[1];
  const float* gw = (const float*)d_in[2];
  const float* gb = (const float*)d_in[3];
  const float* w1 = (const float*)d_in[4];
  const float* b1 = (const float*)d_in[5];
  const float* w2 = (const float*)d_in[6];
  const float* b2 = (const float*)d_in[7];
  float* out = (float*)d_out;

  char* ws = (char*)d_ws;
  half_t* H    = (half_t*)(ws);                        // 32 MB
  half_t* C    = (half_t*)(ws + 33554432);             // KS x 8 MB = 32 MB
  half_t* w1p  = (half_t*)(ws + 67108864);             //  8 MB
  half_t* gw16 = (half_t*)(ws + 75497472);             // 32 KB

  prep_cvt <<<dim3(4112),    dim3(256), 0, stream>>>(w1, w1p, gw, gw16);
  gin_fused<<<dim3(NBS / 4), dim3(256), 0, stream>>>(x, ei, gw16, gb, H);
  lin1_gemm<<<dim3(16 * 4 * KS), dim3(512), 0, stream>>>(H, w1p, C);
  head     <<<dim3(NBS / 4), dim3(256), 0, stream>>>(C, b1, w2, b2, out);
}

// Round 11
// 86.238 us; speedup vs baseline: 1.4101x; 1.0056x over previous
//
#include <hip/hip_runtime.h>

typedef _Float16 half_t;
typedef _Float16 halfv8 __attribute__((ext_vector_type(8)));
typedef _Float16 halfv4 __attribute__((ext_vector_type(4)));
typedef float    floatv4 __attribute__((ext_vector_type(4)));
typedef unsigned int uint;
typedef uint uintv4 __attribute__((ext_vector_type(4)));

#define NODES 32
#define FIN   128
#define EPG   512
#define NBS   4096
#define ETOT  (NBS*EPG)
#define HID   1024
#define KDIM  4096          // FIN*NODES
#define NCLS  10
#define YP    36            // pitch (halves) for Z^T / H^T bounce
#define WP    140           // pitch (halves) for W in LDS

// lin1 GEMM geometry: 128x128 tile, BK=64 (128B rows, XOR-8, 0 conflicts),
// split-K=2, 2 blocks/CU for cross-block latency overlap.
#define BM 128
#define BN 128
#define BK 64
#define KS 2
#define KSLEN (KDIM/KS)  // 2048
#define NT (KSLEN/BK)    // 32 K-tiles

#define GLDS16(g, l)                                                        \
  __builtin_amdgcn_global_load_lds(                                         \
      (const __attribute__((address_space(1))) unsigned int*)(g),           \
      (__attribute__((address_space(3))) unsigned int*)(l), 16, 0, 0)

// ---------------------------------------------------------------------------
// prep: pure fp32->fp16 casts (H layout [g][o*32+m] matches original w1).
__global__ __launch_bounds__(256) void prep_cvt(const float* __restrict__ w1,
                                                half_t* __restrict__ w1p,
                                                const float* __restrict__ gw,
                                                half_t* __restrict__ gw16) {
  const size_t q = (size_t)blockIdx.x * 256 + threadIdx.x;  // 1052672 quads
  const float* s;
  half_t* d;
  size_t off;
  if (q < 1048576) { s = w1; d = w1p; off = q; }
  else             { s = gw; d = gw16; off = q - 1048576; }
  floatv4 v = *(const floatv4*)(s + off * 4);
  halfv4 h = {(half_t)v[0], (half_t)v[1], (half_t)v[2], (half_t)v[3]};
  *(halfv4*)(d + off * 4) = h;
}

// ---------------------------------------------------------------------------
// gin_fused v6 (r10, proven): W block-staged in LDS; Z^T/H^T LDS bounce;
// fat coalesced H stores. Unchanged this round.
__global__ __launch_bounds__(256, 2) void gin_fused(
    const float* __restrict__ x, const int* __restrict__ ei,
    const half_t* __restrict__ gw16, const float* __restrict__ gb,
    half_t* __restrict__ H) {
  __shared__ __attribute__((aligned(16))) half_t Ws[FIN * WP];     // 35840 B
  __shared__ __attribute__((aligned(16))) half_t Yt[4][FIN * YP];  // 36864 B
  __shared__ uint cnt[4][512];                                     //  8192 B

  const int t = threadIdx.x, w = t >> 6, l = t & 63;
  const int lr = l & 15, lk = l >> 4;
  const int g = blockIdx.x * 4 + w;

  const float* xg = x + (size_t)g * (NODES * FIN);
  floatv4 xr[2][4][2];
#pragma unroll
  for (int mt = 0; mt < 2; ++mt)
#pragma unroll
    for (int kk = 0; kk < 4; ++kk) {
      const float* p = xg + (mt * 16 + lr) * FIN + kk * 32 + lk * 8;
      xr[mt][kk][0] = *(const floatv4*)p;
      xr[mt][kk][1] = *(const floatv4*)(p + 4);
    }

  {
    const halfv8* gsrc = (const halfv8*)gw16;
#pragma unroll
    for (int i = 0; i < 8; ++i) {
      const int c = i * 256 + t;
      const int o = c >> 4, f8 = c & 15;
      *(halfv8*)&Ws[o * WP + f8 * 8] = gsrc[c];
    }
  }

  const int* sp = ei + (size_t)g * EPG;
  const int* dp = ei + (size_t)ETOT + (size_t)g * EPG;
  uintv4 s0 = *(const uintv4*)(sp + l * 8);
  uintv4 s1 = *(const uintv4*)(sp + l * 8 + 4);
  uintv4 d0 = *(const uintv4*)(dp + l * 8);
  uintv4 d1 = *(const uintv4*)(dp + l * 8 + 4);

  {
    uintv4* c4 = (uintv4*)cnt[w];
    uintv4 z = {0, 0, 0, 0};
    c4[l] = z;
    c4[l + 64] = z;
  }
#pragma unroll
  for (int q = 0; q < 4; ++q) {
    uint p0 = (d0[q] & 31) * 32 + (s0[q] & 31);
    atomicAdd(&cnt[w][p0 >> 1], 1u << ((p0 & 1) * 16));
    uint p1 = (d1[q] & 31) * 32 + (s1[q] & 31);
    atomicAdd(&cnt[w][p1 >> 1], 1u << ((p1 & 1) * 16));
  }

  halfv8 af[2][4];
#pragma unroll
  for (int mt = 0; mt < 2; ++mt)
#pragma unroll
    for (int kk = 0; kk < 4; ++kk) {
      halfv8 h;
#pragma unroll
      for (int q = 0; q < 4; ++q) {
        h[q]     = (half_t)xr[mt][kk][0][q];
        h[q + 4] = (half_t)xr[mt][kk][1][q];
      }
      af[mt][kk] = h;
    }

  __syncthreads();   // Ws staged (cross-wave)

  floatv4 acc[2][8] = {};
#pragma unroll
  for (int kk = 0; kk < 4; ++kk) {
    halfv8 bfk[8];
#pragma unroll
    for (int nt = 0; nt < 8; ++nt)
      bfk[nt] = *(const halfv8*)&Ws[(nt * 16 + lr) * WP + kk * 32 + lk * 8];
#pragma unroll
    for (int nt = 0; nt < 8; ++nt)
#pragma unroll
      for (int mt = 0; mt < 2; ++mt)
        acc[mt][nt] = __builtin_amdgcn_mfma_f32_16x16x32_f16(af[mt][kk], bfk[nt],
                                                             acc[mt][nt], 0, 0, 0);
  }
  __builtin_amdgcn_sched_barrier(0);

  half_t* yw = Yt[w];
#pragma unroll
  for (int mt = 0; mt < 2; ++mt)
#pragma unroll
    for (int nt = 0; nt < 8; ++nt) {
      halfv4 h = {(half_t)acc[mt][nt][0], (half_t)acc[mt][nt][1],
                  (half_t)acc[mt][nt][2], (half_t)acc[mt][nt][3]};
      *(halfv4*)&yw[(nt * 16 + lr) * YP + mt * 16 + lk * 4] = h;
    }

  const unsigned short* c16 = (const unsigned short*)cnt[w];
  halfv8 am[2];
#pragma unroll
  for (int mt = 0; mt < 2; ++mt) {
    const int i = mt * 16 + lr;
#pragma unroll
    for (int q = 0; q < 8; ++q) {
      const int j = lk * 8 + q;
      float c = (float)c16[i * 32 + j] + ((j == i) ? 1.f : 0.f);
      am[mt][q] = (half_t)c;
    }
  }

  floatv4 acc2[2][8] = {};
#pragma unroll
  for (int nt = 0; nt < 8; ++nt) {
    halfv8 bf = *(const halfv8*)&yw[(nt * 16 + lr) * YP + lk * 8];
#pragma unroll
    for (int mt = 0; mt < 2; ++mt)
      acc2[mt][nt] = __builtin_amdgcn_mfma_f32_16x16x32_f16(am[mt], bf,
                                                            acc2[mt][nt], 0, 0, 0);
  }
  __builtin_amdgcn_sched_barrier(0);

#pragma unroll
  for (int nt = 0; nt < 8; ++nt) {
    const float bias = gb[nt * 16 + lr];
#pragma unroll
    for (int mt = 0; mt < 2; ++mt) {
      halfv4 h;
#pragma unroll
      for (int q = 0; q < 4; ++q) {
        const float v = acc2[mt][nt][q] + bias;
        h[q] = (half_t)(v > 0.f ? v : 0.f);
      }
      *(halfv4*)&yw[(nt * 16 + lr) * YP + mt * 16 + lk * 4] = h;
    }
  }
  __builtin_amdgcn_sched_barrier(0);

  half_t* Hg = H + (size_t)g * KDIM;
#pragma unroll
  for (int c = 0; c < 8; ++c) {
    const int ch = c * 64 + l;
    const int o = ch >> 2, m0 = (ch & 3) * 8;
    halfv8 v = *(const halfv8*)&yw[o * YP + m0];
    *(halfv8*)(Hg + ch * 8) = v;
  }
}

// ---------------------------------------------------------------------------
// lin1 GEMM v6: 128x128 tile, 4 waves, BK=64 (XOR-8, 0 conflicts), dbuf
// 64 KB LDS -> 2 blocks/CU (cross-block latency overlap), split-K=2.
// Per tile: STAGE(next) issued BEFORE compute; one vmcnt(0)+barrier per tile.
// WAR safety: stage targets the buffer whose reads finished last iteration
// (separated by that iteration's end barrier); ds_reads are drained by the
// MFMAs that consume them before the wave reaches the barrier.
__global__ __launch_bounds__(256, 2) void lin1_gemm(
    const half_t* __restrict__ A, const half_t* __restrict__ B,
    half_t* __restrict__ Cbase) {
  __shared__ __attribute__((aligned(16))) half_t As[2][BM * BK];  // 32 KB
  __shared__ __attribute__((aligned(16))) half_t Bs[2][BN * BK];  // 32 KB

  const int t = threadIdx.x;
  const int orig = blockIdx.x;                     // 512 blocks, 2/CU
  const int wg = (orig & 7) * 64 + (orig >> 3);    // bijective XCD swizzle
  const int mt = wg & 31, rest = wg >> 5;          // 32 consecutive mt share B
  const int nt_ = rest & 7, ksz = rest >> 3;
  const int m0 = mt * BM, n0 = nt_ * BN, k0 = ksz * KSLEN;

  // staging: 1024 chunks/operand; thread covers L = t + j*256
  const half_t* gA[4];
  const half_t* gB[4];
#pragma unroll
  for (int j = 0; j < 4; ++j) {
    const int L = t + j * 256;
    const int r = L >> 3;
    const int c = (L & 7) ^ (r & 7);
    gA[j] = A + (size_t)(m0 + r) * KDIM + k0 + c * 8;
    gB[j] = B + (size_t)(n0 + r) * KDIM + k0 + c * 8;
  }

#define STAGE(buf, koff)                                                    \
  {                                                                         \
    _Pragma("unroll")                                                       \
    for (int j = 0; j < 4; ++j)                                             \
      GLDS16(gA[j] + (koff), &As[buf][(t + j * 256) * 8]);                  \
    _Pragma("unroll")                                                       \
    for (int j = 0; j < 4; ++j)                                             \
      GLDS16(gB[j] + (koff), &Bs[buf][(t + j * 256) * 8]);                  \
  }

  const int w = t >> 6, l = t & 63, lr = l & 15, lk = l >> 4;
  const int wm = (w >> 1) * 64, wn = (w & 1) * 64;

  floatv4 acc[4][4] = {};

  // prologue: stage tile 0, gate it
  STAGE(0, 0)
  asm volatile("s_waitcnt vmcnt(0)" ::: "memory");
  __builtin_amdgcn_s_barrier();

  for (int kt = 0; kt < NT; ++kt) {
    const int cur = kt & 1, nxt = cur ^ 1;
    // issue next tile's loads first (latency hides under compute)
    const int kn = (kt + 1 < NT) ? (kt + 1) : 0;   // dummy tail
    STAGE(nxt, kn * BK)
    const half_t* as = As[cur];
    const half_t* bs = Bs[cur];
#pragma unroll
    for (int ksb = 0; ksb < 2; ++ksb) {
      halfv8 af[4], bf[4];
#pragma unroll
      for (int nf = 0; nf < 4; ++nf) {
        const int row = wn + nf * 16 + lr;
        const int ch = (ksb * 4 + lk) ^ (row & 7);
        bf[nf] = *(const halfv8*)&bs[row * BK + ch * 8];
      }
#pragma unroll
      for (int mf = 0; mf < 4; ++mf) {
        const int row = wm + mf * 16 + lr;
        const int ch = (ksb * 4 + lk) ^ (row & 7);
        af[mf] = *(const halfv8*)&as[row * BK + ch * 8];
      }
      __builtin_amdgcn_s_setprio(1);
#pragma unroll
      for (int mf = 0; mf < 4; ++mf)
#pragma unroll
        for (int nf = 0; nf < 4; ++nf)
          acc[mf][nf] = __builtin_amdgcn_mfma_f32_16x16x32_f16(
              af[mf], bf[nf], acc[mf][nf], 0, 0, 0);
      __builtin_amdgcn_s_setprio(0);
    }
    // next tile landed (own slice) + all waves done with cur
    asm volatile("s_waitcnt vmcnt(0)" ::: "memory");
    __builtin_amdgcn_s_barrier();
  }

  // epilogue: fp16 partial store
  half_t* C = Cbase + (size_t)ksz * ((size_t)NBS * HID);
#pragma unroll
  for (int mf = 0; mf < 4; ++mf)
#pragma unroll
    for (int nf = 0; nf < 4; ++nf) {
      const int n = n0 + wn + nf * 16 + lr;
#pragma unroll
      for (int q = 0; q < 4; ++q) {
        const int m = m0 + wm + mf * 16 + lk * 4 + q;
        C[(size_t)m * HID + n] = (half_t)acc[mf][nf][q];
      }
    }
#undef STAGE
}

// ---------------------------------------------------------------------------
// head: hidden = relu(sum_ks C[ks] + b1); logits = hidden @ w2^T + b2; softmax
__global__ __launch_bounds__(256) void head(
    const half_t* __restrict__ Cb, const float* __restrict__ b1,
    const float* __restrict__ w2, const float* __restrict__ b2,
    float* __restrict__ out) {
  __shared__ __attribute__((aligned(16))) float w2s[NCLS * HID];
  const int t = threadIdx.x;
  {
    const floatv4* s4 = (const floatv4*)w2;
    floatv4* d4 = (floatv4*)w2s;
    for (int i = t; i < (NCLS * HID) / 4; i += 256) d4[i] = s4[i];
  }
  __syncthreads();
  const int w = t >> 6, l = t & 63;
  const int row = blockIdx.x * 4 + w;

  float r[16];
#pragma unroll
  for (int jj = 0; jj < 4; ++jj) {
    floatv4 bb = *(const floatv4*)&b1[jj * 256 + l * 4];
    float s[4] = {bb[0], bb[1], bb[2], bb[3]};
#pragma unroll
    for (int p = 0; p < KS; ++p) {
      const half_t* cp = Cb + (size_t)p * ((size_t)NBS * HID) + (size_t)row * HID;
      halfv4 u = *(const halfv4*)&cp[jj * 256 + l * 4];
#pragma unroll
      for (int q = 0; q < 4; ++q) s[q] += (float)u[q];
    }
#pragma unroll
    for (int q = 0; q < 4; ++q) r[jj * 4 + q] = s[q] > 0.f ? s[q] : 0.f;
  }
  float lg[10];
#pragma unroll
  for (int c = 0; c < NCLS; ++c) {
    float p = 0.f;
#pragma unroll
    for (int jj = 0; jj < 4; ++jj) {
      floatv4 wv = *(const floatv4*)&w2s[c * HID + jj * 256 + l * 4];
      p += r[jj * 4 + 0] * wv[0] + r[jj * 4 + 1] * wv[1] +
           r[jj * 4 + 2] * wv[2] + r[jj * 4 + 3] * wv[3];
    }
#pragma unroll
    for (int off = 32; off >= 1; off >>= 1) p += __shfl_xor(p, off);
    lg[c] = p + b2[c];
  }
  float mx = lg[0];
#pragma unroll
  for (int c = 1; c < NCLS; ++c) mx = fmaxf(mx, lg[c]);
  float sum = 0.f;
#pragma unroll
  for (int c = 0; c < NCLS; ++c) { lg[c] = __expf(lg[c] - mx); sum += lg[c]; }
  const float inv = 1.f / sum;
  float myv = 0.f;
#pragma unroll
  for (int c = 0; c < NCLS; ++c) myv = (l == c) ? lg[c] * inv : myv;
  if (l < NCLS) out[(size_t)row * NCLS + l] = myv;
}

// ---------------------------------------------------------------------------
extern "C" void kernel_launch(void* const* d_in, const int* in_sizes, int n_in,
                              void* d_out, int out_size, void* d_ws, size_t ws_size,
                              hipStream_t stream) {
  (void)in_sizes; (void)n_in; (void)out_size; (void)ws_size;
  const float* x  = (const float*)d_in[0];
  const int*   ei = (const int*)d_in[1];
  const float* gw = (const float*)d_in[2];
  const float* gb = (const float*)d_in[3];
  const float* w1 = (const float*)d_in[4];
  const float* b1 = (const float*)d_in[5];
  const float* w2 = (const float*)d_in[6];
  const float* b2 = (const float*)d_in[7];
  float* out = (float*)d_out;

  char* ws = (char*)d_ws;
  half_t* H    = (half_t*)(ws);                        // 32 MB
  half_t* C    = (half_t*)(ws + 33554432);             // KS x 8 MB = 16 MB
  half_t* w1p  = (half_t*)(ws + 67108864);             //  8 MB
  half_t* gw16 = (half_t*)(ws + 75497472);             // 32 KB

  prep_cvt <<<dim3(4112),    dim3(256), 0, stream>>>(w1, w1p, gw, gw16);
  gin_fused<<<dim3(NBS / 4), dim3(256), 0, stream>>>(x, ei, gw16, gb, H);
  lin1_gemm<<<dim3(32 * 8 * KS), dim3(256), 0, stream>>>(H, w1p, C);
  head     <<<dim3(NBS / 4), dim3(256), 0, stream>>>(C, b1, w2, b2, out);
}